// Round 9
// baseline (135.250 us; speedup 1.0000x reference)
//
#include <hip/hip_runtime.h>
#include <math.h>

#define NQ 12
#define DIM 4096
#define NL 6
#define TPB 256

// ---------------------------------------------------------------------------
// R16: two-element software pipeline per block (ILP across independent
// states), on the R15-verified body (R9 structure + lifting butterflies).
//
// R15 post-mortem: VALU floor ~27us vs 79us measured, VALUBusy 50%, LDS pipe
// ~16%, conflicts ~6% -> stall-bound on the serial per-pass chain
// ds_read(latency) -> compute -> ds_write -> barrier x18, with barrier
// convoys defeating TLP. Fix: each block runs TWO elements (2b, 2b+1) in two
// 32KB buffers. Per phase: issue X loads, issue Y loads, compute+store X,
// compute+store Y, ONE shared barrier. X latency hides under Y load issue;
// Y latency hides under X compute (~380cyc); barriers per element halve.
// All address math / tables / lifting RY / diag / fold / init / epilogue are
// byte-identical to R15 (verified this round). LDS 64KB -> 2 blocks/CU
// (8 waves/CU resident; R15's effective occupancy was ~11 anyway), VGPR
// ~64 state + overhead under the (TPB,1) cap=256 (NEVER arg2>=2: R12 spill).
// ---------------------------------------------------------------------------

// ---- d_ws table layout (float offsets) ----
#define WS_WA0 0      // 256 f2  : layer-0 D_phi thread factor e^{i fA0(t)}
#define WS_W   512    // 5*256 f2: merged D_om(l)*D_phi(l+1) thread factor
#define WS_ZA0 3072   // 16 f2   : layer-0 D_phi group factor (label bits 0-3)
#define WS_ZM  3104   // 5*2*16 f2: merged group factor, idx ((l*2+t7)*16+j)
#define WS_RYT 3424   // 72 float4: (w,w,s,s) per (l,wire)  [lifting coeffs]
#define WS_FLOATS 3712  // 14848 bytes total

typedef float f2 __attribute__((ext_vector_type(2)));

__device__ __forceinline__ f2 pk_mul(f2 a, f2 b) {
  f2 d; asm("v_pk_mul_f32 %0, %1, %2" : "=v"(d) : "v"(a), "v"(b)); return d;
}
__device__ __forceinline__ f2 pk_fma(f2 a, f2 b, f2 c) {
  f2 d; asm("v_pk_fma_f32 %0, %1, %2, %3" : "=v"(d) : "v"(a), "v"(b), "v"(c)); return d;
}
// complex mul, both operands packed (re,im)
__device__ __forceinline__ f2 cmulp(f2 a, f2 c) {
  f2 r1, d;
  asm("v_pk_mul_f32 %0, %1, %2 op_sel:[0,0] op_sel_hi:[0,1]"
      : "=v"(r1) : "v"(a), "v"(c));
  asm("v_pk_fma_f32 %0, %1, %2, %3 op_sel:[1,1,0] op_sel_hi:[1,0,1] neg_lo:[1,0,0]"
      : "=v"(d) : "v"(a), "v"(c), "v"(r1));
  return d;
}

// Lifting RY pair update: a += w*b; b += s*a; a += w*b
// == a' = c*a - s*b ; b' = s*a + c*b   (3 pk-FMA vs 4; R15-verified)
template<int BIT>
__device__ __forceinline__ void apply_ry16(f2 v[16], f2 ww, f2 ss) {
  #pragma unroll
  for (int j = 0; j < 16; ++j) {
    if (j & (1 << BIT)) continue;
    const int k = j | (1 << BIT);
    f2 a = v[j], b = v[k];
    a = pk_fma(b, ww, a);
    b = pk_fma(a, ss, b);
    a = pk_fma(b, ww, a);
    v[j] = a; v[k] = b;
  }
}

// ---------------------------------------------------------------------------
// Prep kernel — verbatim R15 (verified this round).
// w layout: w[(l*NQ + q)*3 + c], c: 0=phi, 1=theta, 2=omega.
// ---------------------------------------------------------------------------
__global__ __launch_bounds__(256)
void qprep_kernel(const float* __restrict__ w, float* __restrict__ ws) {
  const int t = threadIdx.x;

  {
    float f = 0.f;
    #pragma unroll
    for (int k = 0; k < 8; ++k) {
      float p = w[(0*NQ + 7 - k)*3 + 0];
      f += ((t >> k) & 1) ? 0.5f*p : -0.5f*p;
    }
    float sv, cv; sincosf(f, &sv, &cv);
    ws[WS_WA0 + 2*t] = cv; ws[WS_WA0 + 2*t + 1] = sv;
  }

  #pragma unroll 1
  for (int l = 0; l < NL-1; ++l) {
    float f = 0.f;
    const int gt = t ^ (t >> 1);
    #pragma unroll
    for (int k = 0; k < 8; ++k) {
      float om = w[(l*NQ + 11 - k)*3 + 2];
      f += ((t >> k) & 1) ? 0.5f*om : -0.5f*om;
    }
    #pragma unroll
    for (int k = 0; k < 7; ++k) {
      float ph = w[((l+1)*NQ + 11 - k)*3 + 0];
      f += ((gt >> k) & 1) ? 0.5f*ph : -0.5f*ph;
    }
    float sv, cv; sincosf(f, &sv, &cv);
    ws[WS_W + (l*256 + t)*2] = cv; ws[WS_W + (l*256 + t)*2 + 1] = sv;
  }

  if (t < 16) {
    float f = 0.f;
    #pragma unroll
    for (int m = 0; m < 4; ++m) {
      float p = w[(0*NQ + 11 - m)*3 + 0];
      f += ((t >> m) & 1) ? 0.5f*p : -0.5f*p;
    }
    float sv, cv; sincosf(f, &sv, &cv);
    ws[WS_ZA0 + 2*t] = cv; ws[WS_ZA0 + 2*t + 1] = sv;
  }

  if (t < 160) {
    const int l = t >> 5, h = (t >> 4) & 1, j = t & 15;
    float f = 0.f;
    #pragma unroll
    for (int m = 0; m < 4; ++m) {
      float om = w[(l*NQ + 3 - m)*3 + 2];
      f += ((j >> m) & 1) ? 0.5f*om : -0.5f*om;
    }
    {
      float p4 = w[((l+1)*NQ + 4)*3 + 0];
      f += (h ^ (j & 1)) ? 0.5f*p4 : -0.5f*p4;
    }
    const int gj = j ^ (j >> 1);
    #pragma unroll
    for (int m = 0; m < 4; ++m) {
      float ph = w[((l+1)*NQ + 3 - m)*3 + 0];
      f += ((gj >> m) & 1) ? 0.5f*ph : -0.5f*ph;
    }
    float sv, cv; sincosf(f, &sv, &cv);
    ws[WS_ZM + 2*t] = cv; ws[WS_ZM + 2*t + 1] = sv;
  }

  // lifting coeffs of the half-angle rotation: s = sin(th/2), w = -tan(th/4)
  if (t < NL*NQ) {
    float th = w[t*3 + 1];
    float sv = sinf(0.5f*th);
    float wv = -tanf(0.25f*th);
    ((float4*)(ws + WS_RYT))[t] = make_float4(wv, wv, sv, sv);
  }
}

// ---- per-pass building blocks (R15 address math, parameterized buffer) ----
#define RYV(V, BIT, WQ) {                                                  \
    const float4 r_ = *(const float4*)(ws + WS_RYT + 4*(l*NQ + (WQ)));     \
    apply_ry16<BIT>(V, (f2){r_.x, r_.y}, (f2){r_.z, r_.w}); }

#define PA_LOAD(V, STB)                                                    \
  _Pragma("unroll")                                                        \
  for (int m = 0; m < 8; ++m) {                                            \
    float4 q4 = *(const float4*)((STB) + baseA[m]);                        \
    V[2*m]   = (f2){q4.x, q4.y};                                           \
    V[2*m+1] = (f2){q4.z, q4.w};                                           \
  }

#define PA_DIAG0(V) {                                                      \
    const float2 wv_ = *(const float2*)(ws + WS_WA0 + 2*t);                \
    const f2 wA0 = (f2){wv_.x, wv_.y};                                     \
    _Pragma("unroll")                                                      \
    for (int j = 0; j < 16; ++j) {                                         \
      const float2 zv = *(const float2*)(ws + WS_ZA0 + 2*j);               \
      V[j] = cmulp(cmulp(V[j], (f2){zv.x, zv.y}), wA0);                    \
    } }

#define PA_RY_STORE(V, STB)                                                \
  RYV(V,0,11) RYV(V,1,10) RYV(V,2,9) RYV(V,3,8)                            \
  _Pragma("unroll")                                                        \
  for (int m = 0; m < 8; ++m)                                              \
    *(float4*)((STB) + baseA[m]) =                                         \
        make_float4(V[2*m].x, V[2*m].y, V[2*m+1].x, V[2*m+1].y);

#define PB_LOAD(V, STB)                                                    \
  _Pragma("unroll")                                                        \
  for (int m = 0; m < 8; ++m) {                                            \
    V[2*m]   = *(const f2*)((STB) + baseB[m] + (2*m)*128);                 \
    V[2*m+1] = *(const f2*)((STB) + baseB[m] + (2*m+1)*128);               \
  }

#define PB_RY_STORE(V, STB)                                                \
  RYV(V,0,7) RYV(V,1,6) RYV(V,2,5) RYV(V,3,4)                              \
  _Pragma("unroll")                                                        \
  for (int m = 0; m < 8; ++m) {                                            \
    *(f2*)((STB) + baseB[m] + (2*m)*128)         = V[2*m];                 \
    *(f2*)((STB) + (baseB[m] ^ 8) + (2*m+1)*128) = V[2*m+1];               \
  }

#define PC_LOAD(V, STB)                                                    \
  _Pragma("unroll")                                                        \
  for (int j = 0; j < 16; ++j)                                             \
    V[j] = *(const f2*)((STB) + baseC + j*2048);

#define PC_RY(V) RYV(V,0,3) RYV(V,1,2) RYV(V,2,1) RYV(V,3,0)

#define PC_DIAG_FOLD(V, STB) {                                             \
    const float2 wv_ = *(const float2*)(ws + WS_W + (l*TPB + t)*2);        \
    const f2 W = (f2){wv_.x, wv_.y};                                       \
    const float* zmb = ws + WS_ZM + ((l*2 + ((t >> 7) & 1))*16)*2;         \
    _Pragma("unroll")                                                      \
    for (int j = 0; j < 16; ++j) {                                         \
      const float2 zv = *(const float2*)(zmb + 2*j);                       \
      V[j] = cmulp(cmulp(V[j], (f2){zv.x, zv.y}), W);                      \
    }                                                                      \
    _Pragma("unroll")                                                      \
    for (int j = 0; j < 16; ++j) {                                         \
      const int g4 = (j ^ (j >> 1)) & 15;                                  \
      *(f2*)((STB) + baseS[j & 1] + (g4 << 11)) = V[j];                    \
    } }

// init: amp(label) = prod_w (bit? sin:cos) * (-i)^popcount * tables
#define INIT_STATE(V, ELEM) {                                              \
    float csx[NQ], csy[NQ];                                                \
    const int q_ = t & 63;                                                 \
    float xv = (q_ < NQ) ? x[(ELEM)*NQ + q_] : 0.f;                        \
    float sv_, cv_; sincosf(0.5f*xv, &sv_, &cv_);                          \
    _Pragma("unroll")                                                      \
    for (int qq = 0; qq < NQ; ++qq) {                                      \
      csx[qq] = __int_as_float(__builtin_amdgcn_readlane(__float_as_int(cv_), qq)); \
      csy[qq] = __int_as_float(__builtin_amdgcn_readlane(__float_as_int(sv_), qq)); \
    }                                                                      \
    float rhi = 1.f;                                                       \
    _Pragma("unroll")                                                      \
    for (int k = 0; k < 8; ++k)                                            \
      rhi *= ((t >> k) & 1) ? csy[7-k] : csx[7-k];                         \
    const int popt = __popc(t);                                            \
    _Pragma("unroll")                                                      \
    for (int j = 0; j < 16; ++j) {                                         \
      float r = rhi;                                                       \
      _Pragma("unroll")                                                    \
      for (int m = 0; m < 4; ++m)                                          \
        r *= ((j >> m) & 1) ? csy[11-m] : csx[11-m];                       \
      const int pj = (popt + __popc(j)) & 3;                               \
      if      (pj == 0) V[j] = (f2){ r, 0.f};                              \
      else if (pj == 1) V[j] = (f2){0.f, -r};                              \
      else if (pj == 2) V[j] = (f2){-r, 0.f};                              \
      else              V[j] = (f2){0.f,  r};                              \
    } }

// ---------------------------------------------------------------------------
// Main kernel: 2 elements per block, two 32KB buffers, shared barriers.
// ---------------------------------------------------------------------------
__global__ __launch_bounds__(TPB, 1)
void qsim12_kernel(const float* __restrict__ x, const float* __restrict__ ws,
                   float* __restrict__ out) {
  __shared__ __align__(16) float st[2][2*DIM];   // 65536 B -> 2 blocks/CU

  const int t = threadIdx.x;
  const int e0 = blockIdx.x*2, e1 = e0 + 1;
  char* stbX = (char*)&st[0][0];
  char* stbY = (char*)&st[1][0];

  // Precomputed byte-address bases (verified R5/R7 — unchanged).
  int baseA[8], baseB[8];
  #pragma unroll
  for (int m = 0; m < 8; ++m) {
    baseA[m] = (t << 7) + (((2*m) ^ (t & 14)) << 3);                 // phys14, A b128
    baseB[m] = ((t >> 4) << 11) + ((((t & 15) ^ (2*m))) << 3);       // + j*128
  }
  const int baseC = ((t >> 4) << 7) + ((((t & 15) ^ ((t >> 4) & 15))) << 3);  // + j*2048
  const int G = t ^ (t >> 1);
  int baseS[2];
  #pragma unroll
  for (int par = 0; par < 2; ++par) {
    const int k8 = par << 3;
    baseS[par] = ((((G >> 4) & 15) ^ k8) << 7)
               + ((((G & 15) ^ ((G >> 4) & 14) ^ k8)) << 3);
  }

  f2 vX[16], vY[16];
  INIT_STATE(vX, e0)
  INIT_STATE(vY, e1)

  #pragma unroll 1
  for (int l = 0; l < NL; ++l) {
    // ---- pass A: wires 11..8 (label bits 0..3)
    if (l > 0) {
      PA_LOAD(vX, stbX)
      PA_LOAD(vY, stbY)
    } else {
      PA_DIAG0(vX)
      PA_DIAG0(vY)
    }
    PA_RY_STORE(vX, stbX)
    PA_RY_STORE(vY, stbY)
    __syncthreads();

    // ---- pass B: wires 7..4 (label bits 4..7); load phys14, store phys15
    PB_LOAD(vX, stbX)
    PB_LOAD(vY, stbY)
    PB_RY_STORE(vX, stbX)
    PB_RY_STORE(vY, stbY)
    __syncthreads();

    // ---- pass C: wires 3..0 (label bits 8..11); load phys15
    PC_LOAD(vX, stbX)
    PC_LOAD(vY, stbY)
    PC_RY(vX)
    PC_RY(vY)
    if (l < NL-1) {
      // merged diag D_om(l)*D_phi(l+1) at post-CNOT label gray(lambda),
      // then fold-store (slot = gray(label), layout phys14)
      PC_DIAG_FOLD(vX, stbX)
      PC_DIAG_FOLD(vY, stbY)
      __syncthreads();
    }
  }

  // ---- Epilogue: labels s = t | j<<8; post-CNOT wire0 = j3, wire1 = j2^j3.
  float a0X = 0.f, a1X = 0.f, a0Y = 0.f, a1Y = 0.f;
  #pragma unroll
  for (int j = 0; j < 16; ++j) {
    float prX = vX[j].x*vX[j].x + vX[j].y*vX[j].y;
    float prY = vY[j].x*vY[j].x + vY[j].y*vY[j].y;
    const float s0 = ((j >> 3) & 1) ? -1.f : 1.f;
    const float s1 = (((j >> 2) ^ (j >> 3)) & 1) ? -1.f : 1.f;
    a0X += s0*prX; a1X += s1*prX;
    a0Y += s0*prY; a1Y += s1*prY;
  }
  #pragma unroll
  for (int off = 32; off >= 1; off >>= 1) {
    a0X += __shfl_down(a0X, off);
    a1X += __shfl_down(a1X, off);
    a0Y += __shfl_down(a0Y, off);
    a1Y += __shfl_down(a1Y, off);
  }
  __syncthreads();                 // all LDS reads done before st reuse
  if ((t & 63) == 0) {
    const int wv = t >> 6;
    st[0][wv*2] = a0X; st[0][wv*2 + 1] = a1X;
    st[1][wv*2] = a0Y; st[1][wv*2 + 1] = a1Y;
  }
  __syncthreads();
  if (t == 0) {
    out[e0*2 + 0] = st[0][0] + st[0][2] + st[0][4] + st[0][6];
    out[e0*2 + 1] = st[0][1] + st[0][3] + st[0][5] + st[0][7];
    out[e1*2 + 0] = st[1][0] + st[1][2] + st[1][4] + st[1][6];
    out[e1*2 + 1] = st[1][1] + st[1][3] + st[1][5] + st[1][7];
  }
}

extern "C" void kernel_launch(void* const* d_in, const int* in_sizes, int n_in,
                              void* d_out, int out_size, void* d_ws, size_t ws_size,
                              hipStream_t stream) {
  const float* x = (const float*)d_in[0];      // (B, 12) f32
  const float* w = (const float*)d_in[1];      // (6, 12, 3) f32
  float* out = (float*)d_out;                  // (B, 2) f32
  float* ws = (float*)d_ws;                    // needs >= 14848 B
  int B = in_sizes[0] / NQ;                    // B = 2048 (even)
  qprep_kernel<<<1, 256, 0, stream>>>(w, ws);
  qsim12_kernel<<<B/2, TPB, 0, stream>>>(x, ws, out);
}